// Round 2
// baseline (169.124 us; speedup 1.0000x reference)
//
#include <hip/hip_runtime.h>

// BasicEuclideanDistModel: two big reductions -> scalar.
// out = N_EVENTS*beta - sum_e ||dz + dv*t_e + EPS||
//       - dt * sum_{p,r} exp(beta - ||dzp + dvp*t_mid[r] + EPS||)

constexpr int N_EVENTS = 8000000;
constexpr int N_PAIRS  = 500000;
constexpr int RSAMP    = 10;
constexpr float EPS    = 1e-6f;

// Block-level reduction (wave64 shuffle + LDS) then one f64 atomic per block.
__device__ __forceinline__ void blockReduceAtomic(double v, double* dst) {
#pragma unroll
    for (int off = 32; off > 0; off >>= 1)
        v += __shfl_down(v, off, 64);
    __shared__ double s[8];
    const int lane = threadIdx.x & 63;
    const int wid  = threadIdx.x >> 6;
    if (lane == 0) s[wid] = v;
    __syncthreads();
    if (threadIdx.x == 0) {
        double r = 0.0;
        const int nw = blockDim.x >> 6;
        for (int i = 0; i < nw; ++i) r += s[i];
        atomicAdd(dst, r);
    }
}

// ---- event term: sum of pairwise distances at event times ----
__global__ void ev_kernel(const float2* __restrict__ z0, const float2* __restrict__ v0,
                          const int4* __restrict__ u4, const int4* __restrict__ v4,
                          const float4* __restrict__ t4, double* __restrict__ ws) {
    const int tid    = blockIdx.x * blockDim.x + threadIdx.x;
    const int stride = gridDim.x * blockDim.x;
    double acc = 0.0;
    for (int i = tid; i < N_EVENTS / 4; i += stride) {
        const int4  uu = u4[i];
        const int4  vv = v4[i];
        const float4 tt = t4[i];
        const int   ua[4] = {uu.x, uu.y, uu.z, uu.w};
        const int   va[4] = {vv.x, vv.y, vv.z, vv.w};
        const float ta[4] = {tt.x, tt.y, tt.z, tt.w};
        float part = 0.f;
#pragma unroll
        for (int k = 0; k < 4; ++k) {
            const float2 zu = z0[ua[k]];
            const float2 zv = z0[va[k]];
            const float2 au = v0[ua[k]];
            const float2 av = v0[va[k]];
            const float dx = (zu.x - zv.x) + (au.x - av.x) * ta[k] + EPS;
            const float dy = (zu.y - zv.y) + (au.y - av.y) * ta[k] + EPS;
            part += sqrtf(dx * dx + dy * dy);
        }
        acc += (double)part;
    }
    blockReduceAtomic(acc, ws + 0);
}

// ---- non-event term: Riemann sum of exp(beta - d) over sampled pairs ----
__global__ void pr_kernel(const float2* __restrict__ z0, const float2* __restrict__ v0,
                          const int* __restrict__ nu, const int* __restrict__ nv,
                          const float* __restrict__ beta, const float* __restrict__ t0p,
                          const float* __restrict__ tnp, double* __restrict__ ws) {
    const int i = blockIdx.x * blockDim.x + threadIdx.x;
    double acc = 0.0;
    if (i < N_PAIRS) {
        const float b  = beta[0];
        const float t0 = t0p[0];
        const float tn = tnp[0];
        const float dt = (tn - t0) / (float)RSAMP;
        const int a = nu[i], c = nv[i];
        const float2 za = z0[a], zc = z0[c];
        const float2 va = v0[a], vc = v0[c];
        const float dzx = za.x - zc.x, dzy = za.y - zc.y;
        const float dvx = va.x - vc.x, dvy = va.y - vc.y;
        float s = 0.f;
#pragma unroll
        for (int r = 0; r < RSAMP; ++r) {
            const float tm = t0 + ((float)r + 0.5f) * dt;
            const float dx = dzx + dvx * tm + EPS;
            const float dy = dzy + dvy * tm + EPS;
            const float d  = sqrtf(dx * dx + dy * dy);
            s += expf(b - d);
        }
        acc = (double)s;
    }
    blockReduceAtomic(acc, ws + 1);
}

// ---- finalize: combine both sums with beta, dt ----
__global__ void fin_kernel(const float* __restrict__ beta, const float* __restrict__ t0p,
                           const float* __restrict__ tnp, const double* __restrict__ ws,
                           float* __restrict__ out) {
    if (threadIdx.x == 0 && blockIdx.x == 0) {
        const double b  = (double)beta[0];
        const double dt = ((double)tnp[0] - (double)t0p[0]) / (double)RSAMP;
        const double ev = (double)N_EVENTS * b - ws[0];
        const double ne = ws[1] * dt;
        out[0] = (float)(ev - ne);
    }
}

extern "C" void kernel_launch(void* const* d_in, const int* in_sizes, int n_in,
                              void* d_out, int out_size, void* d_ws, size_t ws_size,
                              hipStream_t stream) {
    const float*  beta = (const float*)d_in[0];
    const float2* z0   = (const float2*)d_in[1];
    const float2* v0   = (const float2*)d_in[2];
    const int*    u    = (const int*)d_in[3];
    const int*    v    = (const int*)d_in[4];
    const float*  et   = (const float*)d_in[5];
    const int*    nu   = (const int*)d_in[6];
    const int*    nv   = (const int*)d_in[7];
    const float*  t0   = (const float*)d_in[8];
    const float*  tn   = (const float*)d_in[9];
    double* ws = (double*)d_ws;

    hipMemsetAsync(ws, 0, 2 * sizeof(double), stream);
    ev_kernel<<<2048, 256, 0, stream>>>(z0, v0, (const int4*)u, (const int4*)v,
                                        (const float4*)et, ws);
    pr_kernel<<<(N_PAIRS + 255) / 256, 256, 0, stream>>>(z0, v0, nu, nv, beta, t0, tn, ws);
    fin_kernel<<<1, 64, 0, stream>>>(beta, t0, tn, ws, (float*)d_out);
}

// Round 3
// 116.477 us; speedup vs baseline: 1.4520x; 1.4520x over previous
//
#include <hip/hip_runtime.h>

// BasicEuclideanDistModel: two big reductions -> scalar.
// out = N_EVENTS*beta - sum_e ||dz + dv*t_e + EPS||
//       - dt * sum_{p,r} exp(beta - ||dzp + dvp*t_mid[r] + EPS||)
//
// R2: pack z0|v0 into one float4 table (halves scattered lane-requests),
//     8 events/thread-iteration for deeper gather MLP, __expf in pairs kernel.

constexpr int N_POINTS = 100000;
constexpr int N_EVENTS = 8000000;
constexpr int N_PAIRS  = 500000;
constexpr int RSAMP    = 10;
constexpr float EPS    = 1e-6f;

// Block-level reduction (wave64 shuffle + LDS) then one f64 atomic per block.
__device__ __forceinline__ void blockReduceAtomic(double v, double* dst) {
#pragma unroll
    for (int off = 32; off > 0; off >>= 1)
        v += __shfl_down(v, off, 64);
    __shared__ double s[8];
    const int lane = threadIdx.x & 63;
    const int wid  = threadIdx.x >> 6;
    if (lane == 0) s[wid] = v;
    __syncthreads();
    if (threadIdx.x == 0) {
        double r = 0.0;
        const int nw = blockDim.x >> 6;
        for (int i = 0; i < nw; ++i) r += s[i];
        atomicAdd(dst, r);
    }
}

// ---- pack kernel: tab[i] = (z0.x, z0.y, v0.x, v0.y) ----
__global__ void pack_kernel(const float2* __restrict__ z0, const float2* __restrict__ v0,
                            float4* __restrict__ tab) {
    const int i = blockIdx.x * blockDim.x + threadIdx.x;
    if (i < N_POINTS) {
        const float2 z = z0[i];
        const float2 w = v0[i];
        tab[i] = make_float4(z.x, z.y, w.x, w.y);
    }
}

// ---- event term: sum of pairwise distances at event times (8 events/iter) ----
__global__ void ev_packed(const float4* __restrict__ tab,
                          const int4* __restrict__ u4, const int4* __restrict__ v4,
                          const float4* __restrict__ t4, double* __restrict__ ws) {
    const int tid    = blockIdx.x * blockDim.x + threadIdx.x;
    const int stride = gridDim.x * blockDim.x;
    double acc = 0.0;
    const int nIter = N_EVENTS / 8;
    for (int i = tid; i < nIter; i += stride) {
        const int4   uu0 = u4[2 * i], uu1 = u4[2 * i + 1];
        const int4   vv0 = v4[2 * i], vv1 = v4[2 * i + 1];
        const float4 tt0 = t4[2 * i], tt1 = t4[2 * i + 1];
        const int   ua[8] = {uu0.x, uu0.y, uu0.z, uu0.w, uu1.x, uu1.y, uu1.z, uu1.w};
        const int   va[8] = {vv0.x, vv0.y, vv0.z, vv0.w, vv1.x, vv1.y, vv1.z, vv1.w};
        const float ta[8] = {tt0.x, tt0.y, tt0.z, tt0.w, tt1.x, tt1.y, tt1.z, tt1.w};
        float4 pu[8], pv[8];
#pragma unroll
        for (int k = 0; k < 8; ++k) {
            pu[k] = tab[ua[k]];
            pv[k] = tab[va[k]];
        }
        float part = 0.f;
#pragma unroll
        for (int k = 0; k < 8; ++k) {
            const float dx = (pu[k].x - pv[k].x) + (pu[k].z - pv[k].z) * ta[k] + EPS;
            const float dy = (pu[k].y - pv[k].y) + (pu[k].w - pv[k].w) * ta[k] + EPS;
            part += sqrtf(dx * dx + dy * dy);
        }
        acc += (double)part;
    }
    blockReduceAtomic(acc, ws + 0);
}

// ---- non-event term: Riemann sum of exp(beta - d) over sampled pairs ----
__global__ void pr_packed(const float4* __restrict__ tab,
                          const int* __restrict__ nu, const int* __restrict__ nv,
                          const float* __restrict__ beta, const float* __restrict__ t0p,
                          const float* __restrict__ tnp, double* __restrict__ ws) {
    const int i = blockIdx.x * blockDim.x + threadIdx.x;
    double acc = 0.0;
    if (i < N_PAIRS) {
        const float b  = beta[0];
        const float t0 = t0p[0];
        const float tn = tnp[0];
        const float dt = (tn - t0) / (float)RSAMP;
        const float4 pa = tab[nu[i]];
        const float4 pc = tab[nv[i]];
        const float dzx = pa.x - pc.x, dzy = pa.y - pc.y;
        const float dvx = pa.z - pc.z, dvy = pa.w - pc.w;
        float s = 0.f;
#pragma unroll
        for (int r = 0; r < RSAMP; ++r) {
            const float tm = t0 + ((float)r + 0.5f) * dt;
            const float dx = dzx + dvx * tm + EPS;
            const float dy = dzy + dvy * tm + EPS;
            const float d  = sqrtf(dx * dx + dy * dy);
            s += __expf(b - d);
        }
        acc = (double)s;
    }
    blockReduceAtomic(acc, ws + 1);
}

// ---- fallback (unpacked) variants, used only if ws is too small ----
__global__ void ev_kernel(const float2* __restrict__ z0, const float2* __restrict__ v0,
                          const int4* __restrict__ u4, const int4* __restrict__ v4,
                          const float4* __restrict__ t4, double* __restrict__ ws) {
    const int tid    = blockIdx.x * blockDim.x + threadIdx.x;
    const int stride = gridDim.x * blockDim.x;
    double acc = 0.0;
    for (int i = tid; i < N_EVENTS / 4; i += stride) {
        const int4  uu = u4[i];
        const int4  vv = v4[i];
        const float4 tt = t4[i];
        const int   ua[4] = {uu.x, uu.y, uu.z, uu.w};
        const int   va[4] = {vv.x, vv.y, vv.z, vv.w};
        const float ta[4] = {tt.x, tt.y, tt.z, tt.w};
        float part = 0.f;
#pragma unroll
        for (int k = 0; k < 4; ++k) {
            const float2 zu = z0[ua[k]], zv = z0[va[k]];
            const float2 au = v0[ua[k]], av = v0[va[k]];
            const float dx = (zu.x - zv.x) + (au.x - av.x) * ta[k] + EPS;
            const float dy = (zu.y - zv.y) + (au.y - av.y) * ta[k] + EPS;
            part += sqrtf(dx * dx + dy * dy);
        }
        acc += (double)part;
    }
    blockReduceAtomic(acc, ws + 0);
}

__global__ void pr_kernel(const float2* __restrict__ z0, const float2* __restrict__ v0,
                          const int* __restrict__ nu, const int* __restrict__ nv,
                          const float* __restrict__ beta, const float* __restrict__ t0p,
                          const float* __restrict__ tnp, double* __restrict__ ws) {
    const int i = blockIdx.x * blockDim.x + threadIdx.x;
    double acc = 0.0;
    if (i < N_PAIRS) {
        const float b  = beta[0];
        const float t0 = t0p[0];
        const float tn = tnp[0];
        const float dt = (tn - t0) / (float)RSAMP;
        const int a = nu[i], c = nv[i];
        const float2 za = z0[a], zc = z0[c];
        const float2 va = v0[a], vc = v0[c];
        const float dzx = za.x - zc.x, dzy = za.y - zc.y;
        const float dvx = va.x - vc.x, dvy = va.y - vc.y;
        float s = 0.f;
#pragma unroll
        for (int r = 0; r < RSAMP; ++r) {
            const float tm = t0 + ((float)r + 0.5f) * dt;
            const float dx = dzx + dvx * tm + EPS;
            const float dy = dzy + dvy * tm + EPS;
            s += __expf(b - sqrtf(dx * dx + dy * dy));
        }
        acc = (double)s;
    }
    blockReduceAtomic(acc, ws + 1);
}

// ---- finalize: combine both sums with beta, dt ----
__global__ void fin_kernel(const float* __restrict__ beta, const float* __restrict__ t0p,
                           const float* __restrict__ tnp, const double* __restrict__ ws,
                           float* __restrict__ out) {
    if (threadIdx.x == 0 && blockIdx.x == 0) {
        const double b  = (double)beta[0];
        const double dt = ((double)tnp[0] - (double)t0p[0]) / (double)RSAMP;
        const double ev = (double)N_EVENTS * b - ws[0];
        const double ne = ws[1] * dt;
        out[0] = (float)(ev - ne);
    }
}

extern "C" void kernel_launch(void* const* d_in, const int* in_sizes, int n_in,
                              void* d_out, int out_size, void* d_ws, size_t ws_size,
                              hipStream_t stream) {
    const float*  beta = (const float*)d_in[0];
    const float2* z0   = (const float2*)d_in[1];
    const float2* v0   = (const float2*)d_in[2];
    const int*    u    = (const int*)d_in[3];
    const int*    v    = (const int*)d_in[4];
    const float*  et   = (const float*)d_in[5];
    const int*    nu   = (const int*)d_in[6];
    const int*    nv   = (const int*)d_in[7];
    const float*  t0   = (const float*)d_in[8];
    const float*  tn   = (const float*)d_in[9];
    double* ws = (double*)d_ws;

    hipMemsetAsync(ws, 0, 2 * sizeof(double), stream);

    const size_t tab_off   = 256;  // bytes; keeps ws[0..1] doubles clear
    const size_t tab_bytes = (size_t)N_POINTS * sizeof(float4);
    if (ws_size >= tab_off + tab_bytes) {
        float4* tab = (float4*)((char*)d_ws + tab_off);
        pack_kernel<<<(N_POINTS + 255) / 256, 256, 0, stream>>>(z0, v0, tab);
        ev_packed<<<2048, 256, 0, stream>>>(tab, (const int4*)u, (const int4*)v,
                                            (const float4*)et, ws);
        pr_packed<<<(N_PAIRS + 255) / 256, 256, 0, stream>>>(tab, nu, nv, beta, t0, tn, ws);
    } else {
        ev_kernel<<<2048, 256, 0, stream>>>(z0, v0, (const int4*)u, (const int4*)v,
                                            (const float4*)et, ws);
        pr_kernel<<<(N_PAIRS + 255) / 256, 256, 0, stream>>>(z0, v0, nu, nv, beta, t0, tn, ws);
    }
    fin_kernel<<<1, 64, 0, stream>>>(beta, t0, tn, ws, (float*)d_out);
}

// Round 4
// 111.818 us; speedup vs baseline: 1.5125x; 1.0417x over previous
//
#include <hip/hip_runtime.h>

// BasicEuclideanDistModel: two big reductions -> scalar.
// out = N_EVENTS*beta - sum_e ||dz + dv*t_e + EPS||
//       - dt * sum_{p,r} exp(beta - ||dzp + dvp*t_mid[r] + EPS||)
//
// R3: fuse event+pair kernels (co-schedule, kill serialization), 16 events
// per thread (32 gathers in flight -> 2x MLP), ws zeroing folded into pack.

constexpr int N_POINTS = 100000;
constexpr int N_EVENTS = 8000000;
constexpr int N_PAIRS  = 500000;
constexpr int RSAMP    = 10;
constexpr float EPS    = 1e-6f;

constexpr int EV_BATCH  = 16;
constexpr int EV_ITERS  = N_EVENTS / EV_BATCH;            // 500000, exact
constexpr int EV_BLOCKS = (EV_ITERS + 255) / 256;         // 1954
constexpr int PR_BLOCKS = (N_PAIRS + 255) / 256;          // 1954

// Block-level reduction (wave64 shuffle + LDS) then one f64 atomic per block.
__device__ __forceinline__ void blockReduceAtomic(double v, double* dst) {
#pragma unroll
    for (int off = 32; off > 0; off >>= 1)
        v += __shfl_down(v, off, 64);
    __shared__ double s[8];
    const int lane = threadIdx.x & 63;
    const int wid  = threadIdx.x >> 6;
    if (lane == 0) s[wid] = v;
    __syncthreads();
    if (threadIdx.x == 0) {
        double r = 0.0;
        const int nw = blockDim.x >> 6;
        for (int i = 0; i < nw; ++i) r += s[i];
        atomicAdd(dst, r);
    }
}

// ---- pack kernel: tab[i] = (z0.x, z0.y, v0.x, v0.y); also zeroes ws[0..1] ----
__global__ void pack_kernel(const float2* __restrict__ z0, const float2* __restrict__ v0,
                            float4* __restrict__ tab, double* __restrict__ ws) {
    const int i = blockIdx.x * blockDim.x + threadIdx.x;
    if (i < N_POINTS) {
        const float2 z = z0[i];
        const float2 w = v0[i];
        tab[i] = make_float4(z.x, z.y, w.x, w.y);
    }
    if (i < 2) ws[i] = 0.0;
}

// ---- fused: blocks [0,EV_BLOCKS) do events, rest do pair Riemann sum ----
__global__ __launch_bounds__(256, 3)
void fused_kernel(const float4* __restrict__ tab,
                  const int4* __restrict__ u4, const int4* __restrict__ v4,
                  const float4* __restrict__ t4,
                  const int* __restrict__ nu, const int* __restrict__ nv,
                  const float* __restrict__ beta, const float* __restrict__ t0p,
                  const float* __restrict__ tnp, double* __restrict__ ws) {
    if (blockIdx.x < (unsigned)EV_BLOCKS) {
        // ---------------- event distance sum, 16 events/thread ----------------
        const int i = blockIdx.x * blockDim.x + threadIdx.x;
        double acc = 0.0;
        if (i < EV_ITERS) {
            const int base = i * 4;  // in int4/float4 units (4 vecs of 4 = 16 events)
            int4 uu[4], vv[4];
            float4 tt[4];
#pragma unroll
            for (int j = 0; j < 4; ++j) {
                uu[j] = u4[base + j];
                vv[j] = v4[base + j];
                tt[j] = t4[base + j];
            }
            int   ua[16], va[16];
            float ta[16];
#pragma unroll
            for (int j = 0; j < 4; ++j) {
                ua[4 * j + 0] = uu[j].x; ua[4 * j + 1] = uu[j].y;
                ua[4 * j + 2] = uu[j].z; ua[4 * j + 3] = uu[j].w;
                va[4 * j + 0] = vv[j].x; va[4 * j + 1] = vv[j].y;
                va[4 * j + 2] = vv[j].z; va[4 * j + 3] = vv[j].w;
                ta[4 * j + 0] = tt[j].x; ta[4 * j + 1] = tt[j].y;
                ta[4 * j + 2] = tt[j].z; ta[4 * j + 3] = tt[j].w;
            }
            float4 pu[16], pv[16];
#pragma unroll
            for (int k = 0; k < 16; ++k) {
                pu[k] = tab[ua[k]];
                pv[k] = tab[va[k]];
            }
            float part = 0.f;
#pragma unroll
            for (int k = 0; k < 16; ++k) {
                const float dx = (pu[k].x - pv[k].x) + (pu[k].z - pv[k].z) * ta[k] + EPS;
                const float dy = (pu[k].y - pv[k].y) + (pu[k].w - pv[k].w) * ta[k] + EPS;
                part += sqrtf(dx * dx + dy * dy);
            }
            acc = (double)part;
        }
        blockReduceAtomic(acc, ws + 0);
    } else {
        // ---------------- non-event Riemann term ----------------
        const int i = (blockIdx.x - EV_BLOCKS) * blockDim.x + threadIdx.x;
        double acc = 0.0;
        if (i < N_PAIRS) {
            const float b  = beta[0];
            const float t0 = t0p[0];
            const float tn = tnp[0];
            const float dt = (tn - t0) / (float)RSAMP;
            const float4 pa = tab[nu[i]];
            const float4 pc = tab[nv[i]];
            const float dzx = pa.x - pc.x, dzy = pa.y - pc.y;
            const float dvx = pa.z - pc.z, dvy = pa.w - pc.w;
            float s = 0.f;
#pragma unroll
            for (int r = 0; r < RSAMP; ++r) {
                const float tm = t0 + ((float)r + 0.5f) * dt;
                const float dx = dzx + dvx * tm + EPS;
                const float dy = dzy + dvy * tm + EPS;
                s += __expf(b - sqrtf(dx * dx + dy * dy));
            }
            acc = (double)s;
        }
        blockReduceAtomic(acc, ws + 1);
    }
}

// ---- finalize: combine both sums with beta, dt ----
__global__ void fin_kernel(const float* __restrict__ beta, const float* __restrict__ t0p,
                           const float* __restrict__ tnp, const double* __restrict__ ws,
                           float* __restrict__ out) {
    if (threadIdx.x == 0 && blockIdx.x == 0) {
        const double b  = (double)beta[0];
        const double dt = ((double)tnp[0] - (double)t0p[0]) / (double)RSAMP;
        const double ev = (double)N_EVENTS * b - ws[0];
        const double ne = ws[1] * dt;
        out[0] = (float)(ev - ne);
    }
}

extern "C" void kernel_launch(void* const* d_in, const int* in_sizes, int n_in,
                              void* d_out, int out_size, void* d_ws, size_t ws_size,
                              hipStream_t stream) {
    const float*  beta = (const float*)d_in[0];
    const float2* z0   = (const float2*)d_in[1];
    const float2* v0   = (const float2*)d_in[2];
    const int*    u    = (const int*)d_in[3];
    const int*    v    = (const int*)d_in[4];
    const float*  et   = (const float*)d_in[5];
    const int*    nu   = (const int*)d_in[6];
    const int*    nv   = (const int*)d_in[7];
    const float*  t0   = (const float*)d_in[8];
    const float*  tn   = (const float*)d_in[9];
    double* ws = (double*)d_ws;

    const size_t tab_off = 256;  // bytes; keeps ws[0..1] doubles clear
    float4* tab = (float4*)((char*)d_ws + tab_off);

    pack_kernel<<<(N_POINTS + 255) / 256, 256, 0, stream>>>(z0, v0, tab, ws);
    fused_kernel<<<EV_BLOCKS + PR_BLOCKS, 256, 0, stream>>>(
        tab, (const int4*)u, (const int4*)v, (const float4*)et,
        nu, nv, beta, t0, tn, ws);
    fin_kernel<<<1, 64, 0, stream>>>(beta, t0, tn, ws, (float*)d_out);
}